// Round 14
// baseline (47.994 us; speedup 1.0000x reference)
//
#include <hip/hip_runtime.h>

// SSIM v26: v24 skeleton (BY=256, block-coop coalesced gload_lds staging,
// counted vmcnt, ISSUE->VMW->BAR->read ordering) with PAIRED steps:
// 2 chunks per step, 9 steps instead of 17, 6 LDS buffers (72KB).
// Evidence: v24 43.5us best; v25 (no barriers, depth-1) = 47.2 -> cover
// matters, barriers aren't the cost per se. Accounting shows a ~1000+cyc
// fixed cost per step (wait+convergence+restart) paid 17x; pairing halves
// it while keeping v24's cover (VMW(9) leaves 2 chunks = 6 loads in
// flight across each barrier) and the proven cross-wave-safe ordering.
// Buffer hazard: ISSUE(2k+2)->buf((2k+2)%6)=buf((2k-4)%6), whose readers
// (cstep(2k-4), all waves) finished before BAR(k-1) -> race-free with one
// barrier/step. Cost: 2 blocks/CU (LDS 72KB) vs 3 -- v22 showed block
// count is a weak lever. Math byte-identical (absmax exactly 0.0078125).

typedef __attribute__((ext_vector_type(8))) short bf16x8;
typedef __attribute__((ext_vector_type(4))) float f32x4;

constexpr int TX   = 64;             // block out-cols (4 waves x 16)
constexpr int BY   = 256;            // block out-rows
constexpr int IMW  = 512;
constexpr int IMH  = 512;
constexpr int NPL  = 48;
constexpr int GX   = IMW / TX;       // 8
constexpr int GYB  = IMH / BY;       // 2
constexpr int NBLK = GX * GYB * NPL; // 768
constexpr int NCH  = BY / 16;        // 16; chunks 0..16
constexpr int CB   = 12288;          // bytes per chunk buffer (768 float4)
constexpr float C1c = 0.01f * 0.01f;
constexpr float C2c = 0.03f * 0.03f;

union frag {
    bf16x8 f;
    unsigned int u[4];
    uint4 q;
};

// RNE f32->bf16 pair pack (setup kernel only).
__device__ __forceinline__ unsigned int pk_bf16(float lo, float hi) {
    unsigned int a = __float_as_uint(lo);
    unsigned int b = __float_as_uint(hi);
    a += 0x7FFFu + ((a >> 16) & 1u);
    b += 0x7FFFu + ((b >> 16) & 1u);
    return (b & 0xFFFF0000u) | (a >> 16);
}

// Fast pack: round-half-up + byte-perm merge (3 VALU ops per pair).
__device__ __forceinline__ unsigned int pk_rhu(float lo, float hi, unsigned sel) {
    unsigned int a = __float_as_uint(lo) + 0x8000u;
    unsigned int b = __float_as_uint(hi) + 0x8000u;
    unsigned int r;
    asm("v_perm_b32 %0, %1, %2, %3" : "=v"(r) : "v"(b), "v"(a), "s"(sel));
    return r;
}

// Normalized 11-tap Gaussian (sigma=1.5); wt[d] for d in [0,11), else 0.
__device__ __forceinline__ float wsel(int d) {
    float w = 0.f;
    w = (d == 0 || d == 10) ? 0.00102838f : w;
    w = (d == 1 || d == 9)  ? 0.00759876f : w;
    w = (d == 2 || d == 8)  ? 0.03600077f : w;
    w = (d == 3 || d == 7)  ? 0.10936082f : w;
    w = (d == 4 || d == 6)  ? 0.21300553f : w;
    w = (d == 5)            ? 0.26601171f : w;
    return w;
}

// Per-lane weight fragments (8 words/lane):
//   words 0..3: whf  — H-pass B-frag,  W[k][n] = wt[k-n-3],   k = lg*8+j
//   words 4..7: whv  — V-pass A-frag with permuted rows,
//                      W'[k][n] = wt[wr(k)-n-3],
//                      wr(k) = (j<4 ? lg*4+j : 12+lg*4+j), j = k&7
__global__ void ssim_weight_setup(unsigned int* __restrict__ wbuf)
{
    const int lane = threadIdx.x & 63;
    const int ln   = lane & 15;
    const int lg   = lane >> 4;
#pragma unroll
    for (int w = 0; w < 4; ++w) {
        const int ka = lg * 8 + 2 * w;
        wbuf[lane * 8 + w] = pk_bf16(wsel(ka - ln - 3), wsel(ka + 1 - ln - 3));
        const int j0  = 2 * w;
        const int wr0 = (j0 < 4) ? (lg * 4 + j0) : (12 + lg * 4 + j0);
        wbuf[lane * 8 + 4 + w] = pk_bf16(wsel(wr0 - ln - 3), wsel(wr0 + 1 - ln - 3));
    }
}

// H-pass for one chunk from LDS: read 2 f4/img (= v12's 8 fragment floats),
// zero-predicate, pack, 5 MFMAs -> packed D (uint2 per plane).
template<int OFF>
__device__ __forceinline__ void cstep(const char* lds, int ro0, int ro1, bool ok,
                                      const frag& whf, unsigned sel,
                                      uint2* __restrict__ D)
{
    float4 ra0 = *reinterpret_cast<const float4*>(lds + OFF + ro0);
    float4 ra1 = *reinterpret_cast<const float4*>(lds + OFF + ro1);
    float4 rb0 = *reinterpret_cast<const float4*>(lds + OFF + CB / 2 + ro0);
    float4 rb1 = *reinterpret_cast<const float4*>(lds + OFF + CB / 2 + ro1);
    const float4 zz = make_float4(0.f, 0.f, 0.f, 0.f);
    if (!ok) { ra0 = zz; ra1 = zz; rb0 = zz; rb1 = zz; }

    const f32x4 z = {0.f, 0.f, 0.f, 0.f};
    frag fa, fb, faa, fbb, fab;
    fa.u[0]  = pk_rhu(ra0.x, ra0.y, sel);          fb.u[0]  = pk_rhu(rb0.x, rb0.y, sel);
    faa.u[0] = pk_rhu(ra0.x*ra0.x, ra0.y*ra0.y, sel);
    fbb.u[0] = pk_rhu(rb0.x*rb0.x, rb0.y*rb0.y, sel);
    fab.u[0] = pk_rhu(ra0.x*rb0.x, ra0.y*rb0.y, sel);
    fa.u[1]  = pk_rhu(ra0.z, ra0.w, sel);          fb.u[1]  = pk_rhu(rb0.z, rb0.w, sel);
    faa.u[1] = pk_rhu(ra0.z*ra0.z, ra0.w*ra0.w, sel);
    fbb.u[1] = pk_rhu(rb0.z*rb0.z, rb0.w*rb0.w, sel);
    fab.u[1] = pk_rhu(ra0.z*rb0.z, ra0.w*rb0.w, sel);
    fa.u[2]  = pk_rhu(ra1.x, ra1.y, sel);          fb.u[2]  = pk_rhu(rb1.x, rb1.y, sel);
    faa.u[2] = pk_rhu(ra1.x*ra1.x, ra1.y*ra1.y, sel);
    fbb.u[2] = pk_rhu(rb1.x*rb1.x, rb1.y*rb1.y, sel);
    fab.u[2] = pk_rhu(ra1.x*rb1.x, ra1.y*rb1.y, sel);
    fa.u[3]  = pk_rhu(ra1.z, ra1.w, sel);          fb.u[3]  = pk_rhu(rb1.z, rb1.w, sel);
    faa.u[3] = pk_rhu(ra1.z*ra1.z, ra1.w*ra1.w, sel);
    fbb.u[3] = pk_rhu(rb1.z*rb1.z, rb1.w*rb1.w, sel);
    fab.u[3] = pk_rhu(ra1.z*rb1.z, ra1.w*rb1.w, sel);

    f32x4 d;
    d = __builtin_amdgcn_mfma_f32_16x16x32_bf16(fa.f,  whf.f, z, 0, 0, 0);
    D[0] = make_uint2(pk_rhu(d[0], d[1], sel), pk_rhu(d[2], d[3], sel));
    d = __builtin_amdgcn_mfma_f32_16x16x32_bf16(fb.f,  whf.f, z, 0, 0, 0);
    D[1] = make_uint2(pk_rhu(d[0], d[1], sel), pk_rhu(d[2], d[3], sel));
    d = __builtin_amdgcn_mfma_f32_16x16x32_bf16(faa.f, whf.f, z, 0, 0, 0);
    D[2] = make_uint2(pk_rhu(d[0], d[1], sel), pk_rhu(d[2], d[3], sel));
    d = __builtin_amdgcn_mfma_f32_16x16x32_bf16(fbb.f, whf.f, z, 0, 0, 0);
    D[3] = make_uint2(pk_rhu(d[0], d[1], sel), pk_rhu(d[2], d[3], sel));
    d = __builtin_amdgcn_mfma_f32_16x16x32_bf16(fab.f, whf.f, z, 0, 0, 0);
    D[4] = make_uint2(pk_rhu(d[0], d[1], sel), pk_rhu(d[2], d[3], sel));
}

// V-pass for one 16-row out-tile from D_prev (chunk t) + D_cur (chunk t+1).
__device__ __forceinline__ void vstep(const frag& whv,
                                      const uint2* __restrict__ Dp,
                                      const uint2* __restrict__ Dc,
                                      float& lsum)
{
    const f32x4 z = {0.f, 0.f, 0.f, 0.f};
    f32x4 res[5];
#pragma unroll
    for (int p = 0; p < 5; ++p) {
        frag Bf;
        Bf.u[0] = Dp[p].x; Bf.u[1] = Dp[p].y;
        Bf.u[2] = Dc[p].x; Bf.u[3] = Dc[p].y;
        res[p] = __builtin_amdgcn_mfma_f32_16x16x32_bf16(whv.f, Bf.f, z, 0, 0, 0);
    }
#pragma unroll
    for (int j = 0; j < 4; ++j) {
        const float mu1 = res[0][j];
        const float mu2 = res[1][j];
        const float m1s = mu1 * mu1;
        const float m2s = mu2 * mu2;
        const float m12 = mu1 * mu2;
        const float s11 = res[2][j] - m1s;
        const float s22 = res[3][j] - m2s;
        const float s12 = res[4][j] - m12;
        const float num = (2.f * m12 + C1c) * (2.f * s12 + C2c);
        const float den = (m1s + m2s + C1c) * (s11 + s22 + C2c);
        lsum = fmaf(num, __builtin_amdgcn_rcpf(den), lsum);
    }
}

__global__ __launch_bounds__(256, 2)
void ssim_mfma(const float* __restrict__ img1, const float* __restrict__ img2,
               const unsigned int* __restrict__ wbuf,
               float* __restrict__ partials)
{
    const int tid  = threadIdx.x;
    const int lane = tid & 63;
    const int wave = tid >> 6;        // 0..3
    const int ln   = lane & 15;
    const int lg   = lane >> 4;       // 0..3
    const int bx   = blockIdx.x;
    const int y0   = blockIdx.y * BY;
    const float* __restrict__ p1 = img1 + (size_t)blockIdx.z * (IMW * IMH);
    const float* __restrict__ p2 = img2 + (size_t)blockIdx.z * (IMW * IMH);
    const unsigned int sel = 0x07060302u;

    frag whf, whv;
    whf.q = reinterpret_cast<const uint4*>(wbuf)[lane * 2];
    whv.q = reinterpret_cast<const uint4*>(wbuf)[lane * 2 + 1];

    __shared__ __align__(16) char lds[6 * CB];     // 6 chunk buffers (72 KB)
    __shared__ float wsum[4];

    // ---- per-thread load-slot constants (3 groups: L = tid, +256, +512).
    // Lp = L%384; row = Lp/24; slot k = Lp%24 holds seg (k-row)%24 of the
    // window [bx*64-16, +80) (rotate swizzle baked into the SOURCE addr;
    // LDS dest is linear L*16 = wave-uniform base + lane*16 per group).
    const int Lp0 = tid;                       // group0 -> img1
    const int rw0 = Lp0 / 24;
    int sg0 = (Lp0 % 24) - rw0; sg0 += (sg0 < 0) ? 24 : 0;
    int cc0 = bx * TX - 16 + 4 * sg0; cc0 = cc0 < 0 ? 0 : (cc0 > IMW - 4 ? IMW - 4 : cc0);
    const float* gb0 = p1;

    const int L1  = tid + 256;
    const int Lp1 = (L1 < 384) ? L1 : (L1 - 384);
    const int rw1 = Lp1 / 24;
    int sg1 = (Lp1 % 24) - rw1; sg1 += (sg1 < 0) ? 24 : 0;
    int cc1 = bx * TX - 16 + 4 * sg1; cc1 = cc1 < 0 ? 0 : (cc1 > IMW - 4 ? IMW - 4 : cc1);
    const float* gb1 = (L1 < 384) ? p1 : p2;

    const int Lp2 = tid + 512 - 384;           // group2 -> img2
    const int rw2 = Lp2 / 24;
    int sg2 = (Lp2 % 24) - rw2; sg2 += (sg2 < 0) ? 24 : 0;
    int cc2 = bx * TX - 16 + 4 * sg2; cc2 = cc2 < 0 ? 0 : (cc2 > IMW - 4 ? IMW - 4 : cc2);
    const float* gb2 = p2;

    const int wbase = wave * 1024;             // wave-uniform LDS group base

    // ---- fragment read offsets (loop-invariant): row ln, segs s0, s0+1
    const int s0  = 4 * wave + 2 + 2 * lg;
    const int rk0 = (s0 + ln) % 24;
    const int rk1 = (s0 + 1 + ln) % 24;
    const int ro0 = (ln * 24 + rk0) * 16;
    const int ro1 = (ln * 24 + rk1) * 16;
    const int cbase = bx * TX + wave * 16 - 8 + lg * 8;
    const bool colok = ((unsigned)cbase <= (unsigned)(IMW - 8));

    uint2 DA[5], DB[5];
    float lsum = 0.f;

#define CLMP(r) ((r) < 0 ? 0 : ((r) > IMH - 1 ? IMH - 1 : (r)))
#define ISSUE(c, OFF) do{ \
    const int i0 = CLMP(y0 + 16 * (c) - 8 + rw0); \
    const int i1 = CLMP(y0 + 16 * (c) - 8 + rw1); \
    const int i2 = CLMP(y0 + 16 * (c) - 8 + rw2); \
    __builtin_amdgcn_global_load_lds( \
        (const __attribute__((address_space(1))) void*)(gb0 + (size_t)i0 * IMW + cc0), \
        (__attribute__((address_space(3))) void*)(lds + (OFF) + wbase), 16, 0, 0); \
    __builtin_amdgcn_global_load_lds( \
        (const __attribute__((address_space(1))) void*)(gb1 + (size_t)i1 * IMW + cc1), \
        (__attribute__((address_space(3))) void*)(lds + (OFF) + 4096 + wbase), 16, 0, 0); \
    __builtin_amdgcn_global_load_lds( \
        (const __attribute__((address_space(1))) void*)(gb2 + (size_t)i2 * IMW + cc2), \
        (__attribute__((address_space(3))) void*)(lds + (OFF) + 8192 + wbase), 16, 0, 0); \
    } while (0)
#define VMW(n) do{ \
    asm volatile("s_waitcnt vmcnt(" #n ")" ::: "memory"); \
    __builtin_amdgcn_sched_barrier(0); } while (0)
#define BAR() do{ \
    __builtin_amdgcn_sched_barrier(0); \
    __builtin_amdgcn_s_barrier(); \
    __builtin_amdgcn_sched_barrier(0); } while (0)
#define ROWOK(c) (colok && ((unsigned)(y0 + 16 * (c) - 8 + ln) < (unsigned)IMH))

    // ---- prologue: issue chunks 0..3 (12 loads); VMW(9) leaves the 9
    // youngest (chunks 1..3) outstanding -> chunk0 + weight loads retired
    // (in-order vmcnt retirement). BAR -> all waves' chunk0 complete.
    ISSUE(0, 0 * CB);
    ISSUE(1, 1 * CB);
    ISSUE(2, 2 * CB);
    ISSUE(3, 3 * CB);
    VMW(9);
    BAR();
    cstep<0 * CB>(lds, ro0, ro1, ROWOK(0), whf, sel, DA);   // H of chunk 0

    // ---- main march: paired step k processes chunks (2k-1, 2k), emits
    // tiles (2k-2, 2k-1). ISSUE(2k+2),(2k+3) -> bufs reused from 3 steps
    // ago (readers done 2 barriers ago). VMW(9) leaves 3 newest chunks'
    // 9 loads in flight across the barrier. 6-buf cycle repeats every 3
    // steps -> loop u=0..1 of 3 explicit steps (chunks 1..12).
    for (int u = 0; u < 2; ++u) {
        const int b = 6 * u;               // chunk base
        // step: chunks b+1, b+2
        ISSUE(b + 4, 4 * CB); ISSUE(b + 5, 5 * CB); VMW(9); BAR();
        cstep<1 * CB>(lds, ro0, ro1, ROWOK(b + 1), whf, sel, DB);
        vstep(whv, DA, DB, lsum);
        cstep<2 * CB>(lds, ro0, ro1, ROWOK(b + 2), whf, sel, DA);
        vstep(whv, DB, DA, lsum);
        // step: chunks b+3, b+4
        ISSUE(b + 6, 0 * CB); ISSUE(b + 7, 1 * CB); VMW(9); BAR();
        cstep<3 * CB>(lds, ro0, ro1, ROWOK(b + 3), whf, sel, DB);
        vstep(whv, DA, DB, lsum);
        cstep<4 * CB>(lds, ro0, ro1, ROWOK(b + 4), whf, sel, DA);
        vstep(whv, DB, DA, lsum);
        // step: chunks b+5, b+6
        ISSUE(b + 8, 2 * CB); ISSUE(b + 9, 3 * CB); VMW(9); BAR();
        cstep<5 * CB>(lds, ro0, ro1, ROWOK(b + 5), whf, sel, DB);
        vstep(whv, DA, DB, lsum);
        cstep<0 * CB>(lds, ro0, ro1, ROWOK(b + 6), whf, sel, DA);
        vstep(whv, DB, DA, lsum);
    }
    // step: chunks 13, 14 (issue chunk 16 -> buf4; chunk 17 doesn't exist)
    ISSUE(16, 4 * CB); VMW(6); BAR();
    cstep<1 * CB>(lds, ro0, ro1, ROWOK(13), whf, sel, DB);
    vstep(whv, DA, DB, lsum);
    cstep<2 * CB>(lds, ro0, ro1, ROWOK(14), whf, sel, DA);
    vstep(whv, DB, DA, lsum);
    // step: chunks 15, 16
    VMW(0); BAR();
    cstep<3 * CB>(lds, ro0, ro1, ROWOK(15), whf, sel, DB);
    vstep(whv, DA, DB, lsum);
    cstep<4 * CB>(lds, ro0, ro1, ROWOK(16), whf, sel, DA);
    vstep(whv, DB, DA, lsum);
#undef CLMP
#undef ISSUE
#undef VMW
#undef BAR
#undef ROWOK

    // ---- Block reduction -> per-block partial ----
#pragma unroll
    for (int off = 32; off > 0; off >>= 1)
        lsum += __shfl_down(lsum, off, 64);

    if (lane == 0) wsum[wave] = lsum;
    __syncthreads();
    if (tid == 0) {
        float tot = wsum[0] + wsum[1] + wsum[2] + wsum[3];
        const int bid = (blockIdx.z * gridDim.y + blockIdx.y) * gridDim.x + blockIdx.x;
        partials[bid] = tot;
    }
}

__global__ __launch_bounds__(256)
void ssim_reduce_kernel(const float* __restrict__ partials,
                        float* __restrict__ out)
{
    __shared__ double sm[256];
    double s = 0.0;
    for (int i = threadIdx.x; i < NBLK; i += 256) s += (double)partials[i];
    sm[threadIdx.x] = s;
    __syncthreads();
    for (int stride = 128; stride > 0; stride >>= 1) {
        if (threadIdx.x < stride) sm[threadIdx.x] += sm[threadIdx.x + stride];
        __syncthreads();
    }
    if (threadIdx.x == 0) {
        double mean = sm[0] / (double)((size_t)NPL * IMW * IMH);
        out[0] = (float)(1.0 - mean);
    }
}

extern "C" void kernel_launch(void* const* d_in, const int* in_sizes, int n_in,
                              void* d_out, int out_size, void* d_ws, size_t ws_size,
                              hipStream_t stream)
{
    (void)in_sizes; (void)n_in; (void)out_size; (void)ws_size;
    const float* img1 = (const float*)d_in[0];
    const float* img2 = (const float*)d_in[1];
    float* out = (float*)d_out;

    unsigned int* wbuf = (unsigned int*)d_ws;              // 2 KB weight table
    float* partials = (float*)((char*)d_ws + 4096);        // NBLK floats

    ssim_weight_setup<<<1, 64, 0, stream>>>(wbuf);
    dim3 grid(GX, GYB, NPL);
    ssim_mfma<<<grid, 256, 0, stream>>>(img1, img2, wbuf, partials);
    ssim_reduce_kernel<<<1, 256, 0, stream>>>(partials, out);
}

// Round 15
// 44.830 us; speedup vs baseline: 1.0706x; 1.0706x over previous
//
#include <hip/hip_runtime.h>

// SSIM v27: wave-autonomous (ZERO mid-kernel barriers, v25 skeleton) +
// 3 per-wave LDS buffers + sustained depth-2 cover via vmcnt(12).
// Evidence: v24 (convoy, depth-2) 43.5us; v25 (no barriers, depth-1)
// 47.2 -> cover deficit cost 8%; v26 (convoy, 2 blk/CU) 48 -> convoy
// worsens with fewer blocks. v24's wall = SUM of pipe times (15us HBM +
// 16us VALU + 7us LDS/MFMA) because barriers phase-align all waves.
// v27 combines phase-decoupling WITH cover: step c ISSUEs chunk c+2 into
// buf (c+2)%3 (this wave read it at step c-1 -> program-order safe),
// VMW(12) -> chunk c complete, chunks c+1/c+2 (12 loads, 12KB/wave)
// in flight continuously; cover = 2 wave-steps ~3000cyc >> 900cyc HBM.
// 18KB/wave x 4 = 72KB -> 2 blocks/CU; phase-decoupled waves don't
// convoy so the TLP loss is acceptable.  Slot identity + swizzle + math
// byte-identical to v25 (absmax must stay exactly 0.0078125).
//
// Slot identity: instr g of img m, lane 4r+j -> LDS[wave][buf][m][g][r][j]
// holds global (row chunkrow+r, col tx0w-16+4*(4g+(j^(r&3)))). Fragment
// (row ln, cols tx0w-8+8lg..+7) = group g=(2+2lg)>>2, slots
// ((2+2lg)&3)^(ln&3), ((3+2lg)&3)^(ln&3) at row ln.

typedef __attribute__((ext_vector_type(8))) short bf16x8;
typedef __attribute__((ext_vector_type(4))) float f32x4;

constexpr int TX   = 64;             // block out-cols (4 waves x 16)
constexpr int BY   = 256;            // block out-rows
constexpr int IMW  = 512;
constexpr int IMH  = 512;
constexpr int NPL  = 48;
constexpr int GX   = IMW / TX;       // 8
constexpr int GYB  = IMH / BY;       // 2
constexpr int NBLK = GX * GYB * NPL; // 768
constexpr int NCH  = BY / 16;        // 16; chunks 0..16
constexpr int BUF  = 6144;           // bytes per chunk buffer per wave
constexpr int WB   = 3 * BUF;        // per-wave LDS (3 bufs = 18 KB)
constexpr float C1c = 0.01f * 0.01f;
constexpr float C2c = 0.03f * 0.03f;

union frag {
    bf16x8 f;
    unsigned int u[4];
    uint4 q;
};

// RNE f32->bf16 pair pack (setup kernel only).
__device__ __forceinline__ unsigned int pk_bf16(float lo, float hi) {
    unsigned int a = __float_as_uint(lo);
    unsigned int b = __float_as_uint(hi);
    a += 0x7FFFu + ((a >> 16) & 1u);
    b += 0x7FFFu + ((b >> 16) & 1u);
    return (b & 0xFFFF0000u) | (a >> 16);
}

// Fast pack: round-half-up + byte-perm merge (3 VALU ops per pair).
__device__ __forceinline__ unsigned int pk_rhu(float lo, float hi, unsigned sel) {
    unsigned int a = __float_as_uint(lo) + 0x8000u;
    unsigned int b = __float_as_uint(hi) + 0x8000u;
    unsigned int r;
    asm("v_perm_b32 %0, %1, %2, %3" : "=v"(r) : "v"(b), "v"(a), "s"(sel));
    return r;
}

// Normalized 11-tap Gaussian (sigma=1.5); wt[d] for d in [0,11), else 0.
__device__ __forceinline__ float wsel(int d) {
    float w = 0.f;
    w = (d == 0 || d == 10) ? 0.00102838f : w;
    w = (d == 1 || d == 9)  ? 0.00759876f : w;
    w = (d == 2 || d == 8)  ? 0.03600077f : w;
    w = (d == 3 || d == 7)  ? 0.10936082f : w;
    w = (d == 4 || d == 6)  ? 0.21300553f : w;
    w = (d == 5)            ? 0.26601171f : w;
    return w;
}

// Per-lane weight fragments (8 words/lane):
//   words 0..3: whf  — H-pass B-frag,  W[k][n] = wt[k-n-3],   k = lg*8+j
//   words 4..7: whv  — V-pass A-frag with permuted rows,
//                      W'[k][n] = wt[wr(k)-n-3],
//                      wr(k) = (j<4 ? lg*4+j : 12+lg*4+j), j = k&7
__global__ void ssim_weight_setup(unsigned int* __restrict__ wbuf)
{
    const int lane = threadIdx.x & 63;
    const int ln   = lane & 15;
    const int lg   = lane >> 4;
#pragma unroll
    for (int w = 0; w < 4; ++w) {
        const int ka = lg * 8 + 2 * w;
        wbuf[lane * 8 + w] = pk_bf16(wsel(ka - ln - 3), wsel(ka + 1 - ln - 3));
        const int j0  = 2 * w;
        const int wr0 = (j0 < 4) ? (lg * 4 + j0) : (12 + lg * 4 + j0);
        wbuf[lane * 8 + 4 + w] = pk_bf16(wsel(wr0 - ln - 3), wsel(wr0 + 1 - ln - 3));
    }
}

// H-pass for one chunk from this wave's LDS buffer: read 2 f4/img (the
// exact v12 fragment floats), zero-predicate, pack, 5 MFMAs -> packed D.
template<int OFF>
__device__ __forceinline__ void cstep(const char* ldsW, int ro0, int ro1, bool ok,
                                      const frag& whf, unsigned sel,
                                      uint2* __restrict__ D)
{
    float4 ra0 = *reinterpret_cast<const float4*>(ldsW + OFF + ro0);
    float4 ra1 = *reinterpret_cast<const float4*>(ldsW + OFF + ro1);
    float4 rb0 = *reinterpret_cast<const float4*>(ldsW + OFF + 3072 + ro0);
    float4 rb1 = *reinterpret_cast<const float4*>(ldsW + OFF + 3072 + ro1);
    const float4 zz = make_float4(0.f, 0.f, 0.f, 0.f);
    if (!ok) { ra0 = zz; ra1 = zz; rb0 = zz; rb1 = zz; }

    const f32x4 z = {0.f, 0.f, 0.f, 0.f};
    frag fa, fb, faa, fbb, fab;
    fa.u[0]  = pk_rhu(ra0.x, ra0.y, sel);          fb.u[0]  = pk_rhu(rb0.x, rb0.y, sel);
    faa.u[0] = pk_rhu(ra0.x*ra0.x, ra0.y*ra0.y, sel);
    fbb.u[0] = pk_rhu(rb0.x*rb0.x, rb0.y*rb0.y, sel);
    fab.u[0] = pk_rhu(ra0.x*rb0.x, ra0.y*rb0.y, sel);
    fa.u[1]  = pk_rhu(ra0.z, ra0.w, sel);          fb.u[1]  = pk_rhu(rb0.z, rb0.w, sel);
    faa.u[1] = pk_rhu(ra0.z*ra0.z, ra0.w*ra0.w, sel);
    fbb.u[1] = pk_rhu(rb0.z*rb0.z, rb0.w*rb0.w, sel);
    fab.u[1] = pk_rhu(ra0.z*rb0.z, ra0.w*rb0.w, sel);
    fa.u[2]  = pk_rhu(ra1.x, ra1.y, sel);          fb.u[2]  = pk_rhu(rb1.x, rb1.y, sel);
    faa.u[2] = pk_rhu(ra1.x*ra1.x, ra1.y*ra1.y, sel);
    fbb.u[2] = pk_rhu(rb1.x*rb1.x, rb1.y*rb1.y, sel);
    fab.u[2] = pk_rhu(ra1.x*rb1.x, ra1.y*rb1.y, sel);
    fa.u[3]  = pk_rhu(ra1.z, ra1.w, sel);          fb.u[3]  = pk_rhu(rb1.z, rb1.w, sel);
    faa.u[3] = pk_rhu(ra1.z*ra1.z, ra1.w*ra1.w, sel);
    fbb.u[3] = pk_rhu(rb1.z*rb1.z, rb1.w*rb1.w, sel);
    fab.u[3] = pk_rhu(ra1.z*rb1.z, ra1.w*rb1.w, sel);

    f32x4 d;
    d = __builtin_amdgcn_mfma_f32_16x16x32_bf16(fa.f,  whf.f, z, 0, 0, 0);
    D[0] = make_uint2(pk_rhu(d[0], d[1], sel), pk_rhu(d[2], d[3], sel));
    d = __builtin_amdgcn_mfma_f32_16x16x32_bf16(fb.f,  whf.f, z, 0, 0, 0);
    D[1] = make_uint2(pk_rhu(d[0], d[1], sel), pk_rhu(d[2], d[3], sel));
    d = __builtin_amdgcn_mfma_f32_16x16x32_bf16(faa.f, whf.f, z, 0, 0, 0);
    D[2] = make_uint2(pk_rhu(d[0], d[1], sel), pk_rhu(d[2], d[3], sel));
    d = __builtin_amdgcn_mfma_f32_16x16x32_bf16(fbb.f, whf.f, z, 0, 0, 0);
    D[3] = make_uint2(pk_rhu(d[0], d[1], sel), pk_rhu(d[2], d[3], sel));
    d = __builtin_amdgcn_mfma_f32_16x16x32_bf16(fab.f, whf.f, z, 0, 0, 0);
    D[4] = make_uint2(pk_rhu(d[0], d[1], sel), pk_rhu(d[2], d[3], sel));
}

// V-pass for one 16-row out-tile from D_prev (chunk t) + D_cur (chunk t+1).
__device__ __forceinline__ void vstep(const frag& whv,
                                      const uint2* __restrict__ Dp,
                                      const uint2* __restrict__ Dc,
                                      float& lsum)
{
    const f32x4 z = {0.f, 0.f, 0.f, 0.f};
    f32x4 res[5];
#pragma unroll
    for (int p = 0; p < 5; ++p) {
        frag Bf;
        Bf.u[0] = Dp[p].x; Bf.u[1] = Dp[p].y;
        Bf.u[2] = Dc[p].x; Bf.u[3] = Dc[p].y;
        res[p] = __builtin_amdgcn_mfma_f32_16x16x32_bf16(whv.f, Bf.f, z, 0, 0, 0);
    }
#pragma unroll
    for (int j = 0; j < 4; ++j) {
        const float mu1 = res[0][j];
        const float mu2 = res[1][j];
        const float m1s = mu1 * mu1;
        const float m2s = mu2 * mu2;
        const float m12 = mu1 * mu2;
        const float s11 = res[2][j] - m1s;
        const float s22 = res[3][j] - m2s;
        const float s12 = res[4][j] - m12;
        const float num = (2.f * m12 + C1c) * (2.f * s12 + C2c);
        const float den = (m1s + m2s + C1c) * (s11 + s22 + C2c);
        lsum = fmaf(num, __builtin_amdgcn_rcpf(den), lsum);
    }
}

__global__ __launch_bounds__(256, 2)
void ssim_mfma(const float* __restrict__ img1, const float* __restrict__ img2,
               const unsigned int* __restrict__ wbuf,
               float* __restrict__ partials)
{
    const int tid  = threadIdx.x;
    const int lane = tid & 63;
    const int wave = tid >> 6;        // 0..3
    const int ln   = lane & 15;
    const int lg   = lane >> 4;       // 0..3
    const int bx   = blockIdx.x;
    const int y0   = blockIdx.y * BY;
    const float* __restrict__ p1 = img1 + (size_t)blockIdx.z * (IMW * IMH);
    const float* __restrict__ p2 = img2 + (size_t)blockIdx.z * (IMW * IMH);
    const unsigned int sel = 0x07060302u;

    frag whf, whv;
    whf.q = reinterpret_cast<const uint4*>(wbuf)[lane * 2];
    whv.q = reinterpret_cast<const uint4*>(wbuf)[lane * 2 + 1];

    __shared__ __align__(16) char lds[4 * WB];     // 18 KB per wave (72 KB)
    __shared__ float wsum[4];
    const int wbase = wave * WB;
    const char* ldsW = lds + wbase;

    // ---- per-lane load constants: lane = 4r+j loads (row r, seg 4g+js)
    // of the wave window [tx0w-16, +48) floats; js = j ^ (r&3) (XOR bank
    // swizzle, within-line so coalescing is unaffected: 16 lines/instr).
    const int rr  = lane >> 2;
    const int jj  = lane & 3;
    const int js  = jj ^ (rr & 3);
    const int cA16 = bx * TX + wave * 16 - 16;     // 64B-aligned window base
    int cg0 = cA16 + 4 * (0 + js); cg0 = cg0 < 0 ? 0 : (cg0 > IMW - 4 ? IMW - 4 : cg0);
    int cg1 = cA16 + 4 * (4 + js); cg1 = cg1 < 0 ? 0 : (cg1 > IMW - 4 ? IMW - 4 : cg1);
    int cg2 = cA16 + 4 * (8 + js); cg2 = cg2 < 0 ? 0 : (cg2 > IMW - 4 ? IMW - 4 : cg2);

    // ---- fragment read offsets (loop-invariant): abs seg s0 = 2+2lg.
    const int s0 = 2 + 2 * lg;
    const int gg = s0 >> 2;
    const int ro0 = gg * 1024 + ln * 64 + (((s0 & 3) ^ (ln & 3)) << 4);
    const int ro1 = gg * 1024 + ln * 64 + ((((s0 + 1) & 3) ^ (ln & 3)) << 4);
    const int cbase = bx * TX + wave * 16 - 8 + lg * 8;
    const bool colok = ((unsigned)cbase <= (unsigned)(IMW - 8));

    uint2 DA[5], DB[5];
    float lsum = 0.f;

#define CLMP(r) ((r) < 0 ? 0 : ((r) > IMH - 1 ? IMH - 1 : (r)))
#define ISSUE(c, OFF) do{ \
    const int ir = CLMP(y0 + 16 * (c) - 8 + rr); \
    const float* r1 = p1 + (size_t)ir * IMW; \
    const float* r2 = p2 + (size_t)ir * IMW; \
    __builtin_amdgcn_global_load_lds( \
        (const __attribute__((address_space(1))) void*)(r1 + cg0), \
        (__attribute__((address_space(3))) void*)(lds + wbase + (OFF) + 0), 16, 0, 0); \
    __builtin_amdgcn_global_load_lds( \
        (const __attribute__((address_space(1))) void*)(r1 + cg1), \
        (__attribute__((address_space(3))) void*)(lds + wbase + (OFF) + 1024), 16, 0, 0); \
    __builtin_amdgcn_global_load_lds( \
        (const __attribute__((address_space(1))) void*)(r1 + cg2), \
        (__attribute__((address_space(3))) void*)(lds + wbase + (OFF) + 2048), 16, 0, 0); \
    __builtin_amdgcn_global_load_lds( \
        (const __attribute__((address_space(1))) void*)(r2 + cg0), \
        (__attribute__((address_space(3))) void*)(lds + wbase + (OFF) + 3072), 16, 0, 0); \
    __builtin_amdgcn_global_load_lds( \
        (const __attribute__((address_space(1))) void*)(r2 + cg1), \
        (__attribute__((address_space(3))) void*)(lds + wbase + (OFF) + 4096), 16, 0, 0); \
    __builtin_amdgcn_global_load_lds( \
        (const __attribute__((address_space(1))) void*)(r2 + cg2), \
        (__attribute__((address_space(3))) void*)(lds + wbase + (OFF) + 5120), 16, 0, 0); \
    } while (0)
#define VMW(n) do{ \
    asm volatile("s_waitcnt vmcnt(" #n ")" ::: "memory"); \
    __builtin_amdgcn_sched_barrier(0); } while (0)
#define ROWOK(c) (colok && ((unsigned)(y0 + 16 * (c) - 8 + ln) < (unsigned)IMH))

    // ---- prologue: chunks 0,1 in flight; step 0 issues chunk 2 and
    // waits vmcnt(12) -> chunk 0 complete, 1..2 (12 loads) stay out.
    ISSUE(0, 0 * BUF);
    ISSUE(1, 1 * BUF);
    ISSUE(2, 2 * BUF);
    VMW(12);
    cstep<0 * BUF>(ldsW, ro0, ro1, ROWOK(0), whf, sel, DA);

    // ---- main march, NO barriers, depth-2 sustained: step c issues
    // chunk c+2 into buf (c+2)%3 (this wave read it at step c-1 ->
    // program-order safe), VMW(12) completes chunk c only.
    for (int u = 0; u < 2; ++u) {          // c = 6u+1 .. 6u+6  (1..12)
        ISSUE(6 * u + 3, 0 * BUF); VMW(12);
        cstep<1 * BUF>(ldsW, ro0, ro1, ROWOK(6 * u + 1), whf, sel, DB);
        vstep(whv, DA, DB, lsum);
        ISSUE(6 * u + 4, 1 * BUF); VMW(12);
        cstep<2 * BUF>(ldsW, ro0, ro1, ROWOK(6 * u + 2), whf, sel, DA);
        vstep(whv, DB, DA, lsum);
        ISSUE(6 * u + 5, 2 * BUF); VMW(12);
        cstep<0 * BUF>(ldsW, ro0, ro1, ROWOK(6 * u + 3), whf, sel, DB);
        vstep(whv, DA, DB, lsum);
        ISSUE(6 * u + 6, 0 * BUF); VMW(12);
        cstep<1 * BUF>(ldsW, ro0, ro1, ROWOK(6 * u + 4), whf, sel, DA);
        vstep(whv, DB, DA, lsum);
        ISSUE(6 * u + 7, 1 * BUF); VMW(12);
        cstep<2 * BUF>(ldsW, ro0, ro1, ROWOK(6 * u + 5), whf, sel, DB);
        vstep(whv, DA, DB, lsum);
        ISSUE(6 * u + 8, 2 * BUF); VMW(12);
        cstep<0 * BUF>(ldsW, ro0, ro1, ROWOK(6 * u + 6), whf, sel, DA);
        vstep(whv, DB, DA, lsum);
    }
    // c = 13
    ISSUE(15, 0 * BUF); VMW(12);
    cstep<1 * BUF>(ldsW, ro0, ro1, ROWOK(13), whf, sel, DB);
    vstep(whv, DA, DB, lsum);
    // c = 14
    ISSUE(16, 1 * BUF); VMW(12);
    cstep<2 * BUF>(ldsW, ro0, ro1, ROWOK(14), whf, sel, DA);
    vstep(whv, DB, DA, lsum);
    // c = 15 (chunks 15,16 = 12 loads outstanding; complete chunk 15)
    VMW(6);
    cstep<0 * BUF>(ldsW, ro0, ro1, ROWOK(15), whf, sel, DB);
    vstep(whv, DA, DB, lsum);
    // c = 16
    VMW(0);
    cstep<1 * BUF>(ldsW, ro0, ro1, ROWOK(16), whf, sel, DA);
    vstep(whv, DB, DA, lsum);
#undef CLMP
#undef ISSUE
#undef VMW
#undef ROWOK

    // ---- Block reduction -> per-block partial (only barrier in kernel) ----
#pragma unroll
    for (int off = 32; off > 0; off >>= 1)
        lsum += __shfl_down(lsum, off, 64);

    if (lane == 0) wsum[wave] = lsum;
    __syncthreads();
    if (tid == 0) {
        float tot = wsum[0] + wsum[1] + wsum[2] + wsum[3];
        const int bid = (blockIdx.z * gridDim.y + blockIdx.y) * gridDim.x + blockIdx.x;
        partials[bid] = tot;
    }
}

__global__ __launch_bounds__(256)
void ssim_reduce_kernel(const float* __restrict__ partials,
                        float* __restrict__ out)
{
    __shared__ double sm[256];
    double s = 0.0;
    for (int i = threadIdx.x; i < NBLK; i += 256) s += (double)partials[i];
    sm[threadIdx.x] = s;
    __syncthreads();
    for (int stride = 128; stride > 0; stride >>= 1) {
        if (threadIdx.x < stride) sm[threadIdx.x] += sm[threadIdx.x + stride];
        __syncthreads();
    }
    if (threadIdx.x == 0) {
        double mean = sm[0] / (double)((size_t)NPL * IMW * IMH);
        out[0] = (float)(1.0 - mean);
    }
}

extern "C" void kernel_launch(void* const* d_in, const int* in_sizes, int n_in,
                              void* d_out, int out_size, void* d_ws, size_t ws_size,
                              hipStream_t stream)
{
    (void)in_sizes; (void)n_in; (void)out_size; (void)ws_size;
    const float* img1 = (const float*)d_in[0];
    const float* img2 = (const float*)d_in[1];
    float* out = (float*)d_out;

    unsigned int* wbuf = (unsigned int*)d_ws;              // 2 KB weight table
    float* partials = (float*)((char*)d_ws + 4096);        // NBLK floats

    ssim_weight_setup<<<1, 64, 0, stream>>>(wbuf);
    dim3 grid(GX, GYB, NPL);
    ssim_mfma<<<grid, 256, 0, stream>>>(img1, img2, wbuf, partials);
    ssim_reduce_kernel<<<1, 256, 0, stream>>>(partials, out);
}

// Round 16
// 42.757 us; speedup vs baseline: 1.1225x; 1.0485x over previous
//
#include <hip/hip_runtime.h>

// SSIM v28: v24 structure UNCHANGED (best, 43.5us: BY=256, block-coop
// coalesced gload_lds staging, quad LDS buffer, counted vmcnt(6),
// ISSUE->VMW->BAR->read) with all hot-path f32->bf16 packing switched
// from 3-op pk_rhu (add,add,v_perm) to single-op v_cvt_pk_bf16_f32 via
// __builtin_convertvector (true vector fptrunc -> compiler emits the
// native cvt_pk; avoids v15's hand-asm NaN and follows m240's finding
// that the compiler path beats hand asm). Cuts 60 of ~190 VALU ops per
// chunk (-33% VALU). R12-R15 exhausted sync-structure space (barriers/
// depth/step-size/blocks all +-10% of 43.5) -> wall = per-wave serial
// sum (15us HBM + 16.7us VALU + 7us LDS/MFMA); VALU is the largest
// reducible term. Numerics: RHU->RNE, pointwise <=0.5ulp, matches the
// weight table's RNE; threshold headroom 2.5x.

#include <hip/hip_runtime.h>

typedef __attribute__((ext_vector_type(8))) short bf16x8;
typedef __attribute__((ext_vector_type(4))) float f32x4;
typedef __attribute__((ext_vector_type(2))) float f32x2;
typedef __attribute__((ext_vector_type(2))) __bf16 bfx2;

constexpr int TX   = 64;             // block out-cols (4 waves x 16)
constexpr int BY   = 256;            // block out-rows
constexpr int IMW  = 512;
constexpr int IMH  = 512;
constexpr int NPL  = 48;
constexpr int GX   = IMW / TX;       // 8
constexpr int GYB  = IMH / BY;       // 2
constexpr int NBLK = GX * GYB * NPL; // 768
constexpr int NCH  = BY / 16;        // 16; chunks 0..16
constexpr int CB   = 12288;          // bytes per chunk buffer (768 float4)
constexpr float C1c = 0.01f * 0.01f;
constexpr float C2c = 0.03f * 0.03f;

union frag {
    bf16x8 f;
    unsigned int u[4];
    uint4 q;
};

// RNE f32->bf16 pair pack, software (setup kernel only; bit-identical to HW RNE).
__device__ __forceinline__ unsigned int pk_bf16(float lo, float hi) {
    unsigned int a = __float_as_uint(lo);
    unsigned int b = __float_as_uint(hi);
    a += 0x7FFFu + ((a >> 16) & 1u);
    b += 0x7FFFu + ((b >> 16) & 1u);
    return (b & 0xFFFF0000u) | (a >> 16);
}

// HW RNE pair pack: vector fptrunc -> v_cvt_pk_bf16_f32 (1 VALU op).
__device__ __forceinline__ unsigned int pk_rne(float lo, float hi) {
    f32x2 v; v.x = lo; v.y = hi;
    bfx2 b = __builtin_convertvector(v, bfx2);
    return *reinterpret_cast<unsigned int*>(&b);
}

// Normalized 11-tap Gaussian (sigma=1.5); wt[d] for d in [0,11), else 0.
__device__ __forceinline__ float wsel(int d) {
    float w = 0.f;
    w = (d == 0 || d == 10) ? 0.00102838f : w;
    w = (d == 1 || d == 9)  ? 0.00759876f : w;
    w = (d == 2 || d == 8)  ? 0.03600077f : w;
    w = (d == 3 || d == 7)  ? 0.10936082f : w;
    w = (d == 4 || d == 6)  ? 0.21300553f : w;
    w = (d == 5)            ? 0.26601171f : w;
    return w;
}

// Per-lane weight fragments (8 words/lane):
//   words 0..3: whf  — H-pass B-frag,  W[k][n] = wt[k-n-3],   k = lg*8+j
//   words 4..7: whv  — V-pass A-frag with permuted rows,
//                      W'[k][n] = wt[wr(k)-n-3],
//                      wr(k) = (j<4 ? lg*4+j : 12+lg*4+j), j = k&7
__global__ void ssim_weight_setup(unsigned int* __restrict__ wbuf)
{
    const int lane = threadIdx.x & 63;
    const int ln   = lane & 15;
    const int lg   = lane >> 4;
#pragma unroll
    for (int w = 0; w < 4; ++w) {
        const int ka = lg * 8 + 2 * w;
        wbuf[lane * 8 + w] = pk_bf16(wsel(ka - ln - 3), wsel(ka + 1 - ln - 3));
        const int j0  = 2 * w;
        const int wr0 = (j0 < 4) ? (lg * 4 + j0) : (12 + lg * 4 + j0);
        wbuf[lane * 8 + 4 + w] = pk_bf16(wsel(wr0 - ln - 3), wsel(wr0 + 1 - ln - 3));
    }
}

// H-pass for one chunk from LDS: read 2 f4/img (= v12's 8 fragment floats),
// zero-predicate, pack (RNE cvt_pk), 5 MFMAs -> packed D (uint2 per plane).
template<int OFF>
__device__ __forceinline__ void cstep(const char* lds, int ro0, int ro1, bool ok,
                                      const frag& whf,
                                      uint2* __restrict__ D)
{
    float4 ra0 = *reinterpret_cast<const float4*>(lds + OFF + ro0);
    float4 ra1 = *reinterpret_cast<const float4*>(lds + OFF + ro1);
    float4 rb0 = *reinterpret_cast<const float4*>(lds + OFF + CB / 2 + ro0);
    float4 rb1 = *reinterpret_cast<const float4*>(lds + OFF + CB / 2 + ro1);
    const float4 zz = make_float4(0.f, 0.f, 0.f, 0.f);
    if (!ok) { ra0 = zz; ra1 = zz; rb0 = zz; rb1 = zz; }

    const f32x4 z = {0.f, 0.f, 0.f, 0.f};
    frag fa, fb, faa, fbb, fab;
    fa.u[0]  = pk_rne(ra0.x, ra0.y);               fb.u[0]  = pk_rne(rb0.x, rb0.y);
    faa.u[0] = pk_rne(ra0.x*ra0.x, ra0.y*ra0.y);
    fbb.u[0] = pk_rne(rb0.x*rb0.x, rb0.y*rb0.y);
    fab.u[0] = pk_rne(ra0.x*rb0.x, ra0.y*rb0.y);
    fa.u[1]  = pk_rne(ra0.z, ra0.w);               fb.u[1]  = pk_rne(rb0.z, rb0.w);
    faa.u[1] = pk_rne(ra0.z*ra0.z, ra0.w*ra0.w);
    fbb.u[1] = pk_rne(rb0.z*rb0.z, rb0.w*rb0.w);
    fab.u[1] = pk_rne(ra0.z*rb0.z, ra0.w*rb0.w);
    fa.u[2]  = pk_rne(ra1.x, ra1.y);               fb.u[2]  = pk_rne(rb1.x, rb1.y);
    faa.u[2] = pk_rne(ra1.x*ra1.x, ra1.y*ra1.y);
    fbb.u[2] = pk_rne(rb1.x*rb1.x, rb1.y*rb1.y);
    fab.u[2] = pk_rne(ra1.x*rb1.x, ra1.y*rb1.y);
    fa.u[3]  = pk_rne(ra1.z, ra1.w);               fb.u[3]  = pk_rne(rb1.z, rb1.w);
    faa.u[3] = pk_rne(ra1.z*ra1.z, ra1.w*ra1.w);
    fbb.u[3] = pk_rne(rb1.z*rb1.z, rb1.w*rb1.w);
    fab.u[3] = pk_rne(ra1.z*rb1.z, ra1.w*rb1.w);

    f32x4 d;
    d = __builtin_amdgcn_mfma_f32_16x16x32_bf16(fa.f,  whf.f, z, 0, 0, 0);
    D[0] = make_uint2(pk_rne(d[0], d[1]), pk_rne(d[2], d[3]));
    d = __builtin_amdgcn_mfma_f32_16x16x32_bf16(fb.f,  whf.f, z, 0, 0, 0);
    D[1] = make_uint2(pk_rne(d[0], d[1]), pk_rne(d[2], d[3]));
    d = __builtin_amdgcn_mfma_f32_16x16x32_bf16(faa.f, whf.f, z, 0, 0, 0);
    D[2] = make_uint2(pk_rne(d[0], d[1]), pk_rne(d[2], d[3]));
    d = __builtin_amdgcn_mfma_f32_16x16x32_bf16(fbb.f, whf.f, z, 0, 0, 0);
    D[3] = make_uint2(pk_rne(d[0], d[1]), pk_rne(d[2], d[3]));
    d = __builtin_amdgcn_mfma_f32_16x16x32_bf16(fab.f, whf.f, z, 0, 0, 0);
    D[4] = make_uint2(pk_rne(d[0], d[1]), pk_rne(d[2], d[3]));
}

// V-pass for one 16-row out-tile from D_prev (chunk t) + D_cur (chunk t+1).
__device__ __forceinline__ void vstep(const frag& whv,
                                      const uint2* __restrict__ Dp,
                                      const uint2* __restrict__ Dc,
                                      float& lsum)
{
    const f32x4 z = {0.f, 0.f, 0.f, 0.f};
    f32x4 res[5];
#pragma unroll
    for (int p = 0; p < 5; ++p) {
        frag Bf;
        Bf.u[0] = Dp[p].x; Bf.u[1] = Dp[p].y;
        Bf.u[2] = Dc[p].x; Bf.u[3] = Dc[p].y;
        res[p] = __builtin_amdgcn_mfma_f32_16x16x32_bf16(whv.f, Bf.f, z, 0, 0, 0);
    }
#pragma unroll
    for (int j = 0; j < 4; ++j) {
        const float mu1 = res[0][j];
        const float mu2 = res[1][j];
        const float m1s = mu1 * mu1;
        const float m2s = mu2 * mu2;
        const float m12 = mu1 * mu2;
        const float s11 = res[2][j] - m1s;
        const float s22 = res[3][j] - m2s;
        const float s12 = res[4][j] - m12;
        const float num = (2.f * m12 + C1c) * (2.f * s12 + C2c);
        const float den = (m1s + m2s + C1c) * (s11 + s22 + C2c);
        lsum = fmaf(num, __builtin_amdgcn_rcpf(den), lsum);
    }
}

__global__ __launch_bounds__(256, 3)
void ssim_mfma(const float* __restrict__ img1, const float* __restrict__ img2,
               const unsigned int* __restrict__ wbuf,
               float* __restrict__ partials)
{
    const int tid  = threadIdx.x;
    const int lane = tid & 63;
    const int wave = tid >> 6;        // 0..3
    const int ln   = lane & 15;
    const int lg   = lane >> 4;       // 0..3
    const int bx   = blockIdx.x;
    const int y0   = blockIdx.y * BY;
    const float* __restrict__ p1 = img1 + (size_t)blockIdx.z * (IMW * IMH);
    const float* __restrict__ p2 = img2 + (size_t)blockIdx.z * (IMW * IMH);

    frag whf, whv;
    whf.q = reinterpret_cast<const uint4*>(wbuf)[lane * 2];
    whv.q = reinterpret_cast<const uint4*>(wbuf)[lane * 2 + 1];

    __shared__ __align__(16) char lds[4 * CB];     // 4 chunk buffers
    __shared__ float wsum[4];

    // ---- per-thread load-slot constants (3 groups: L = tid, +256, +512).
    // Lp = L%384; row = Lp/24; slot k = Lp%24 holds seg (k-row)%24 of the
    // window [bx*64-16, +80) (rotate swizzle baked into the SOURCE addr;
    // LDS dest is linear L*16 = wave-uniform base + lane*16 per group).
    const int Lp0 = tid;                       // group0 -> img1
    const int rw0 = Lp0 / 24;
    int sg0 = (Lp0 % 24) - rw0; sg0 += (sg0 < 0) ? 24 : 0;
    int cc0 = bx * TX - 16 + 4 * sg0; cc0 = cc0 < 0 ? 0 : (cc0 > IMW - 4 ? IMW - 4 : cc0);
    const float* gb0 = p1;

    const int L1  = tid + 256;
    const int Lp1 = (L1 < 384) ? L1 : (L1 - 384);
    const int rw1 = Lp1 / 24;
    int sg1 = (Lp1 % 24) - rw1; sg1 += (sg1 < 0) ? 24 : 0;
    int cc1 = bx * TX - 16 + 4 * sg1; cc1 = cc1 < 0 ? 0 : (cc1 > IMW - 4 ? IMW - 4 : cc1);
    const float* gb1 = (L1 < 384) ? p1 : p2;

    const int Lp2 = tid + 512 - 384;           // group2 -> img2
    const int rw2 = Lp2 / 24;
    int sg2 = (Lp2 % 24) - rw2; sg2 += (sg2 < 0) ? 24 : 0;
    int cc2 = bx * TX - 16 + 4 * sg2; cc2 = cc2 < 0 ? 0 : (cc2 > IMW - 4 ? IMW - 4 : cc2);
    const float* gb2 = p2;

    const int wbase = wave * 1024;             // wave-uniform LDS group base

    // ---- fragment read offsets (loop-invariant): row ln, segs s0, s0+1
    const int s0  = 4 * wave + 2 + 2 * lg;
    const int rk0 = (s0 + ln) % 24;
    const int rk1 = (s0 + 1 + ln) % 24;
    const int ro0 = (ln * 24 + rk0) * 16;
    const int ro1 = (ln * 24 + rk1) * 16;
    const int cbase = bx * TX + wave * 16 - 8 + lg * 8;
    const bool colok = ((unsigned)cbase <= (unsigned)(IMW - 8));

    uint2 DA[5], DB[5];
    float lsum = 0.f;

#define CLMP(r) ((r) < 0 ? 0 : ((r) > IMH - 1 ? IMH - 1 : (r)))
#define ISSUE(c, OFF) do{ \
    const int i0 = CLMP(y0 + 16 * (c) - 8 + rw0); \
    const int i1 = CLMP(y0 + 16 * (c) - 8 + rw1); \
    const int i2 = CLMP(y0 + 16 * (c) - 8 + rw2); \
    __builtin_amdgcn_global_load_lds( \
        (const __attribute__((address_space(1))) void*)(gb0 + (size_t)i0 * IMW + cc0), \
        (__attribute__((address_space(3))) void*)(lds + (OFF) + wbase), 16, 0, 0); \
    __builtin_amdgcn_global_load_lds( \
        (const __attribute__((address_space(1))) void*)(gb1 + (size_t)i1 * IMW + cc1), \
        (__attribute__((address_space(3))) void*)(lds + (OFF) + 4096 + wbase), 16, 0, 0); \
    __builtin_amdgcn_global_load_lds( \
        (const __attribute__((address_space(1))) void*)(gb2 + (size_t)i2 * IMW + cc2), \
        (__attribute__((address_space(3))) void*)(lds + (OFF) + 8192 + wbase), 16, 0, 0); \
    } while (0)
#define VMW(n) do{ \
    asm volatile("s_waitcnt vmcnt(" #n ")" ::: "memory"); \
    __builtin_amdgcn_sched_barrier(0); } while (0)
#define BAR() do{ \
    __builtin_amdgcn_sched_barrier(0); \
    __builtin_amdgcn_s_barrier(); \
    __builtin_amdgcn_sched_barrier(0); } while (0)
#define ROWOK(c) (colok && ((unsigned)(y0 + 16 * (c) - 8 + ln) < (unsigned)IMH))

    // ---- prologue: issue chunks 0..2 (9 loads out); wait chunk0; H(0).
    ISSUE(0, 0 * CB);
    ISSUE(1, 1 * CB);
    ISSUE(2, 2 * CB);
    VMW(6);                                // chunk0 writes complete
    BAR();
    cstep<0 * CB>(lds, ro0, ro1, ROWOK(0), whf, DA);   // H of chunk 0

    // ---- main march: step c: ISSUE(c+2 -> buf[(c+2)%4]); vmcnt(6) ->
    // chunk c done, c+1/c+2 in flight across the barrier; cstep(chunk c,
    // buf[c%4]); vstep(tile c-1). Buf reuse separated by step c-1's BAR.
    for (int u = 0; u < 3; ++u) {          // c = 4u+1 .. 4u+4  (1..12)
        const int c0 = 4 * u;
        ISSUE(c0 + 3, 3 * CB); VMW(6); BAR();
        cstep<1 * CB>(lds, ro0, ro1, ROWOK(c0 + 1), whf, DB);
        vstep(whv, DA, DB, lsum);
        ISSUE(c0 + 4, 0 * CB); VMW(6); BAR();
        cstep<2 * CB>(lds, ro0, ro1, ROWOK(c0 + 2), whf, DA);
        vstep(whv, DB, DA, lsum);
        ISSUE(c0 + 5, 1 * CB); VMW(6); BAR();
        cstep<3 * CB>(lds, ro0, ro1, ROWOK(c0 + 3), whf, DB);
        vstep(whv, DA, DB, lsum);
        ISSUE(c0 + 6, 2 * CB); VMW(6); BAR();
        cstep<0 * CB>(lds, ro0, ro1, ROWOK(c0 + 4), whf, DA);
        vstep(whv, DB, DA, lsum);
    }
    // c = 13
    ISSUE(15, 3 * CB); VMW(6); BAR();
    cstep<1 * CB>(lds, ro0, ro1, ROWOK(13), whf, DB);
    vstep(whv, DA, DB, lsum);
    // c = 14
    ISSUE(16, 0 * CB); VMW(6); BAR();
    cstep<2 * CB>(lds, ro0, ro1, ROWOK(14), whf, DA);
    vstep(whv, DB, DA, lsum);
    // c = 15 (no issue; chunk16's 3 loads outstanding)
    VMW(3); BAR();
    cstep<3 * CB>(lds, ro0, ro1, ROWOK(15), whf, DB);
    vstep(whv, DA, DB, lsum);
    // c = 16
    VMW(0); BAR();
    cstep<0 * CB>(lds, ro0, ro1, ROWOK(16), whf, DA);
    vstep(whv, DB, DA, lsum);
#undef CLMP
#undef ISSUE
#undef VMW
#undef BAR
#undef ROWOK

    // ---- Block reduction -> per-block partial ----
#pragma unroll
    for (int off = 32; off > 0; off >>= 1)
        lsum += __shfl_down(lsum, off, 64);

    if (lane == 0) wsum[wave] = lsum;
    __syncthreads();
    if (tid == 0) {
        float tot = wsum[0] + wsum[1] + wsum[2] + wsum[3];
        const int bid = (blockIdx.z * gridDim.y + blockIdx.y) * gridDim.x + blockIdx.x;
        partials[bid] = tot;
    }
}

__global__ __launch_bounds__(256)
void ssim_reduce_kernel(const float* __restrict__ partials,
                        float* __restrict__ out)
{
    __shared__ double sm[256];
    double s = 0.0;
    for (int i = threadIdx.x; i < NBLK; i += 256) s += (double)partials[i];
    sm[threadIdx.x] = s;
    __syncthreads();
    for (int stride = 128; stride > 0; stride >>= 1) {
        if (threadIdx.x < stride) sm[threadIdx.x] += sm[threadIdx.x + stride];
        __syncthreads();
    }
    if (threadIdx.x == 0) {
        double mean = sm[0] / (double)((size_t)NPL * IMW * IMH);
        out[0] = (float)(1.0 - mean);
    }
}

extern "C" void kernel_launch(void* const* d_in, const int* in_sizes, int n_in,
                              void* d_out, int out_size, void* d_ws, size_t ws_size,
                              hipStream_t stream)
{
    (void)in_sizes; (void)n_in; (void)out_size; (void)ws_size;
    const float* img1 = (const float*)d_in[0];
    const float* img2 = (const float*)d_in[1];
    float* out = (float*)d_out;

    unsigned int* wbuf = (unsigned int*)d_ws;              // 2 KB weight table
    float* partials = (float*)((char*)d_ws + 4096);        // NBLK floats

    ssim_weight_setup<<<1, 64, 0, stream>>>(wbuf);
    dim3 grid(GX, GYB, NPL);
    ssim_mfma<<<grid, 256, 0, stream>>>(img1, img2, wbuf, partials);
    ssim_reduce_kernel<<<1, 256, 0, stream>>>(partials, out);
}

// Round 17
// 33.260 us; speedup vs baseline: 1.4430x; 1.2855x over previous
//
#include <hip/hip_runtime.h>

// SSIM v29: v28 (best, 42.8us: gload_lds quad-buffer, counted vmcnt(6),
// cvt_pk RNE packing) + XCD-locality block swizzle (T1, bijective).
// Invariant across v12-v28: useful READ delivery never exceeds ~2.2 TB/s
// (occupancy 18-62%, depth 1-3, barriers 0-17, two layouts) -> per-CU
// read line-fill concurrency cap (~8KB in flight @ ~900ns = 2.3 TB/s).
// Only lower fill LATENCY raises it. Adjacent-bx blocks share a 32-col
// halo (1/3 of reads); default dispatch round-robins linear IDs across
// XCDs so halo partners sit on different L2s (both fetch @ L3/HBM
// latency). v29: 1D grid h in [0,768); xcd=h&7, slot=h>>3,
// pair=xcd*12+slot/8, bx=slot&7, by=pair&1, bz=pair>>1 (bijective:
// 768 = 8 XCDs x 96). All 8 bx of 12 row-strips land on ONE XCD ->
// halo re-reads hit local L2 (~200cy vs ~900cy), freeing fill slots
// ~4x faster for 1/3 of requests -> cap +~25%.
// Math + partial grouping byte-identical (absmax exactly 0.0078125).

typedef __attribute__((ext_vector_type(8))) short bf16x8;
typedef __attribute__((ext_vector_type(4))) float f32x4;
typedef __attribute__((ext_vector_type(2))) float f32x2;
typedef __attribute__((ext_vector_type(2))) __bf16 bfx2;

constexpr int TX   = 64;             // block out-cols (4 waves x 16)
constexpr int BY   = 256;            // block out-rows
constexpr int IMW  = 512;
constexpr int IMH  = 512;
constexpr int NPL  = 48;
constexpr int GX   = IMW / TX;       // 8
constexpr int GYB  = IMH / BY;       // 2
constexpr int NBLK = GX * GYB * NPL; // 768
constexpr int NCH  = BY / 16;        // 16; chunks 0..16
constexpr int CB   = 12288;          // bytes per chunk buffer (768 float4)
constexpr float C1c = 0.01f * 0.01f;
constexpr float C2c = 0.03f * 0.03f;

union frag {
    bf16x8 f;
    unsigned int u[4];
    uint4 q;
};

// RNE f32->bf16 pair pack, software (setup kernel only; bit-identical to HW RNE).
__device__ __forceinline__ unsigned int pk_bf16(float lo, float hi) {
    unsigned int a = __float_as_uint(lo);
    unsigned int b = __float_as_uint(hi);
    a += 0x7FFFu + ((a >> 16) & 1u);
    b += 0x7FFFu + ((b >> 16) & 1u);
    return (b & 0xFFFF0000u) | (a >> 16);
}

// HW RNE pair pack: vector fptrunc -> v_cvt_pk_bf16_f32 (1 VALU op).
__device__ __forceinline__ unsigned int pk_rne(float lo, float hi) {
    f32x2 v; v.x = lo; v.y = hi;
    bfx2 b = __builtin_convertvector(v, bfx2);
    return *reinterpret_cast<unsigned int*>(&b);
}

// Normalized 11-tap Gaussian (sigma=1.5); wt[d] for d in [0,11), else 0.
__device__ __forceinline__ float wsel(int d) {
    float w = 0.f;
    w = (d == 0 || d == 10) ? 0.00102838f : w;
    w = (d == 1 || d == 9)  ? 0.00759876f : w;
    w = (d == 2 || d == 8)  ? 0.03600077f : w;
    w = (d == 3 || d == 7)  ? 0.10936082f : w;
    w = (d == 4 || d == 6)  ? 0.21300553f : w;
    w = (d == 5)            ? 0.26601171f : w;
    return w;
}

// Per-lane weight fragments (8 words/lane):
//   words 0..3: whf  — H-pass B-frag,  W[k][n] = wt[k-n-3],   k = lg*8+j
//   words 4..7: whv  — V-pass A-frag with permuted rows,
//                      W'[k][n] = wt[wr(k)-n-3],
//                      wr(k) = (j<4 ? lg*4+j : 12+lg*4+j), j = k&7
__global__ void ssim_weight_setup(unsigned int* __restrict__ wbuf)
{
    const int lane = threadIdx.x & 63;
    const int ln   = lane & 15;
    const int lg   = lane >> 4;
#pragma unroll
    for (int w = 0; w < 4; ++w) {
        const int ka = lg * 8 + 2 * w;
        wbuf[lane * 8 + w] = pk_bf16(wsel(ka - ln - 3), wsel(ka + 1 - ln - 3));
        const int j0  = 2 * w;
        const int wr0 = (j0 < 4) ? (lg * 4 + j0) : (12 + lg * 4 + j0);
        wbuf[lane * 8 + 4 + w] = pk_bf16(wsel(wr0 - ln - 3), wsel(wr0 + 1 - ln - 3));
    }
}

// H-pass for one chunk from LDS: read 2 f4/img (= v12's 8 fragment floats),
// zero-predicate, pack (RNE cvt_pk), 5 MFMAs -> packed D (uint2 per plane).
template<int OFF>
__device__ __forceinline__ void cstep(const char* lds, int ro0, int ro1, bool ok,
                                      const frag& whf,
                                      uint2* __restrict__ D)
{
    float4 ra0 = *reinterpret_cast<const float4*>(lds + OFF + ro0);
    float4 ra1 = *reinterpret_cast<const float4*>(lds + OFF + ro1);
    float4 rb0 = *reinterpret_cast<const float4*>(lds + OFF + CB / 2 + ro0);
    float4 rb1 = *reinterpret_cast<const float4*>(lds + OFF + CB / 2 + ro1);
    const float4 zz = make_float4(0.f, 0.f, 0.f, 0.f);
    if (!ok) { ra0 = zz; ra1 = zz; rb0 = zz; rb1 = zz; }

    const f32x4 z = {0.f, 0.f, 0.f, 0.f};
    frag fa, fb, faa, fbb, fab;
    fa.u[0]  = pk_rne(ra0.x, ra0.y);               fb.u[0]  = pk_rne(rb0.x, rb0.y);
    faa.u[0] = pk_rne(ra0.x*ra0.x, ra0.y*ra0.y);
    fbb.u[0] = pk_rne(rb0.x*rb0.x, rb0.y*rb0.y);
    fab.u[0] = pk_rne(ra0.x*rb0.x, ra0.y*rb0.y);
    fa.u[1]  = pk_rne(ra0.z, ra0.w);               fb.u[1]  = pk_rne(rb0.z, rb0.w);
    faa.u[1] = pk_rne(ra0.z*ra0.z, ra0.w*ra0.w);
    fbb.u[1] = pk_rne(rb0.z*rb0.z, rb0.w*rb0.w);
    fab.u[1] = pk_rne(ra0.z*rb0.z, ra0.w*rb0.w);
    fa.u[2]  = pk_rne(ra1.x, ra1.y);               fb.u[2]  = pk_rne(rb1.x, rb1.y);
    faa.u[2] = pk_rne(ra1.x*ra1.x, ra1.y*ra1.y);
    fbb.u[2] = pk_rne(rb1.x*rb1.x, rb1.y*rb1.y);
    fab.u[2] = pk_rne(ra1.x*rb1.x, ra1.y*rb1.y);
    fa.u[3]  = pk_rne(ra1.z, ra1.w);               fb.u[3]  = pk_rne(rb1.z, rb1.w);
    faa.u[3] = pk_rne(ra1.z*ra1.z, ra1.w*ra1.w);
    fbb.u[3] = pk_rne(rb1.z*rb1.z, rb1.w*rb1.w);
    fab.u[3] = pk_rne(ra1.z*rb1.z, ra1.w*rb1.w);

    f32x4 d;
    d = __builtin_amdgcn_mfma_f32_16x16x32_bf16(fa.f,  whf.f, z, 0, 0, 0);
    D[0] = make_uint2(pk_rne(d[0], d[1]), pk_rne(d[2], d[3]));
    d = __builtin_amdgcn_mfma_f32_16x16x32_bf16(fb.f,  whf.f, z, 0, 0, 0);
    D[1] = make_uint2(pk_rne(d[0], d[1]), pk_rne(d[2], d[3]));
    d = __builtin_amdgcn_mfma_f32_16x16x32_bf16(faa.f, whf.f, z, 0, 0, 0);
    D[2] = make_uint2(pk_rne(d[0], d[1]), pk_rne(d[2], d[3]));
    d = __builtin_amdgcn_mfma_f32_16x16x32_bf16(fbb.f, whf.f, z, 0, 0, 0);
    D[3] = make_uint2(pk_rne(d[0], d[1]), pk_rne(d[2], d[3]));
    d = __builtin_amdgcn_mfma_f32_16x16x32_bf16(fab.f, whf.f, z, 0, 0, 0);
    D[4] = make_uint2(pk_rne(d[0], d[1]), pk_rne(d[2], d[3]));
}

// V-pass for one 16-row out-tile from D_prev (chunk t) + D_cur (chunk t+1).
__device__ __forceinline__ void vstep(const frag& whv,
                                      const uint2* __restrict__ Dp,
                                      const uint2* __restrict__ Dc,
                                      float& lsum)
{
    const f32x4 z = {0.f, 0.f, 0.f, 0.f};
    f32x4 res[5];
#pragma unroll
    for (int p = 0; p < 5; ++p) {
        frag Bf;
        Bf.u[0] = Dp[p].x; Bf.u[1] = Dp[p].y;
        Bf.u[2] = Dc[p].x; Bf.u[3] = Dc[p].y;
        res[p] = __builtin_amdgcn_mfma_f32_16x16x32_bf16(whv.f, Bf.f, z, 0, 0, 0);
    }
#pragma unroll
    for (int j = 0; j < 4; ++j) {
        const float mu1 = res[0][j];
        const float mu2 = res[1][j];
        const float m1s = mu1 * mu1;
        const float m2s = mu2 * mu2;
        const float m12 = mu1 * mu2;
        const float s11 = res[2][j] - m1s;
        const float s22 = res[3][j] - m2s;
        const float s12 = res[4][j] - m12;
        const float num = (2.f * m12 + C1c) * (2.f * s12 + C2c);
        const float den = (m1s + m2s + C1c) * (s11 + s22 + C2c);
        lsum = fmaf(num, __builtin_amdgcn_rcpf(den), lsum);
    }
}

__global__ __launch_bounds__(256, 3)
void ssim_mfma(const float* __restrict__ img1, const float* __restrict__ img2,
               const unsigned int* __restrict__ wbuf,
               float* __restrict__ partials)
{
    const int tid  = threadIdx.x;
    const int lane = tid & 63;
    const int wave = tid >> 6;        // 0..3
    const int ln   = lane & 15;
    const int lg   = lane >> 4;       // 0..3

    // ---- XCD-locality decode (bijective, 768 = 8 XCDs x 96 slots).
    // Dispatcher round-robins linear h across XCDs -> h&7 ~ XCD id.
    // All 8 bx of 12 (by,bz) row-strips land on one XCD so adjacent-bx
    // halo reads (1/3 of traffic) hit that XCD's L2.
    const int h    = blockIdx.x;
    const int xcd  = h & 7;
    const int slot = h >> 3;              // 0..95
    const int pr   = xcd * 12 + (slot >> 3);   // 0..95 (by,bz) pair
    const int bx   = slot & 7;
    const int by   = pr & 1;
    const int bz   = pr >> 1;

    const int y0   = by * BY;
    const float* __restrict__ p1 = img1 + (size_t)bz * (IMW * IMH);
    const float* __restrict__ p2 = img2 + (size_t)bz * (IMW * IMH);

    frag whf, whv;
    whf.q = reinterpret_cast<const uint4*>(wbuf)[lane * 2];
    whv.q = reinterpret_cast<const uint4*>(wbuf)[lane * 2 + 1];

    __shared__ __align__(16) char lds[4 * CB];     // 4 chunk buffers
    __shared__ float wsum[4];

    // ---- per-thread load-slot constants (3 groups: L = tid, +256, +512).
    // Lp = L%384; row = Lp/24; slot k = Lp%24 holds seg (k-row)%24 of the
    // window [bx*64-16, +80) (rotate swizzle baked into the SOURCE addr;
    // LDS dest is linear L*16 = wave-uniform base + lane*16 per group).
    const int Lp0 = tid;                       // group0 -> img1
    const int rw0 = Lp0 / 24;
    int sg0 = (Lp0 % 24) - rw0; sg0 += (sg0 < 0) ? 24 : 0;
    int cc0 = bx * TX - 16 + 4 * sg0; cc0 = cc0 < 0 ? 0 : (cc0 > IMW - 4 ? IMW - 4 : cc0);
    const float* gb0 = p1;

    const int L1  = tid + 256;
    const int Lp1 = (L1 < 384) ? L1 : (L1 - 384);
    const int rw1 = Lp1 / 24;
    int sg1 = (Lp1 % 24) - rw1; sg1 += (sg1 < 0) ? 24 : 0;
    int cc1 = bx * TX - 16 + 4 * sg1; cc1 = cc1 < 0 ? 0 : (cc1 > IMW - 4 ? IMW - 4 : cc1);
    const float* gb1 = (L1 < 384) ? p1 : p2;

    const int Lp2 = tid + 512 - 384;           // group2 -> img2
    const int rw2 = Lp2 / 24;
    int sg2 = (Lp2 % 24) - rw2; sg2 += (sg2 < 0) ? 24 : 0;
    int cc2 = bx * TX - 16 + 4 * sg2; cc2 = cc2 < 0 ? 0 : (cc2 > IMW - 4 ? IMW - 4 : cc2);
    const float* gb2 = p2;

    const int wbase = wave * 1024;             // wave-uniform LDS group base

    // ---- fragment read offsets (loop-invariant): row ln, segs s0, s0+1
    const int s0  = 4 * wave + 2 + 2 * lg;
    const int rk0 = (s0 + ln) % 24;
    const int rk1 = (s0 + 1 + ln) % 24;
    const int ro0 = (ln * 24 + rk0) * 16;
    const int ro1 = (ln * 24 + rk1) * 16;
    const int cbase = bx * TX + wave * 16 - 8 + lg * 8;
    const bool colok = ((unsigned)cbase <= (unsigned)(IMW - 8));

    uint2 DA[5], DB[5];
    float lsum = 0.f;

#define CLMP(r) ((r) < 0 ? 0 : ((r) > IMH - 1 ? IMH - 1 : (r)))
#define ISSUE(c, OFF) do{ \
    const int i0 = CLMP(y0 + 16 * (c) - 8 + rw0); \
    const int i1 = CLMP(y0 + 16 * (c) - 8 + rw1); \
    const int i2 = CLMP(y0 + 16 * (c) - 8 + rw2); \
    __builtin_amdgcn_global_load_lds( \
        (const __attribute__((address_space(1))) void*)(gb0 + (size_t)i0 * IMW + cc0), \
        (__attribute__((address_space(3))) void*)(lds + (OFF) + wbase), 16, 0, 0); \
    __builtin_amdgcn_global_load_lds( \
        (const __attribute__((address_space(1))) void*)(gb1 + (size_t)i1 * IMW + cc1), \
        (__attribute__((address_space(3))) void*)(lds + (OFF) + 4096 + wbase), 16, 0, 0); \
    __builtin_amdgcn_global_load_lds( \
        (const __attribute__((address_space(1))) void*)(gb2 + (size_t)i2 * IMW + cc2), \
        (__attribute__((address_space(3))) void*)(lds + (OFF) + 8192 + wbase), 16, 0, 0); \
    } while (0)
#define VMW(n) do{ \
    asm volatile("s_waitcnt vmcnt(" #n ")" ::: "memory"); \
    __builtin_amdgcn_sched_barrier(0); } while (0)
#define BAR() do{ \
    __builtin_amdgcn_sched_barrier(0); \
    __builtin_amdgcn_s_barrier(); \
    __builtin_amdgcn_sched_barrier(0); } while (0)
#define ROWOK(c) (colok && ((unsigned)(y0 + 16 * (c) - 8 + ln) < (unsigned)IMH))

    // ---- prologue: issue chunks 0..2 (9 loads out); wait chunk0; H(0).
    ISSUE(0, 0 * CB);
    ISSUE(1, 1 * CB);
    ISSUE(2, 2 * CB);
    VMW(6);                                // chunk0 writes complete
    BAR();
    cstep<0 * CB>(lds, ro0, ro1, ROWOK(0), whf, DA);   // H of chunk 0

    // ---- main march: step c: ISSUE(c+2 -> buf[(c+2)%4]); vmcnt(6) ->
    // chunk c done, c+1/c+2 in flight across the barrier; cstep(chunk c,
    // buf[c%4]); vstep(tile c-1). Buf reuse separated by step c-1's BAR.
    for (int u = 0; u < 3; ++u) {          // c = 4u+1 .. 4u+4  (1..12)
        const int c0 = 4 * u;
        ISSUE(c0 + 3, 3 * CB); VMW(6); BAR();
        cstep<1 * CB>(lds, ro0, ro1, ROWOK(c0 + 1), whf, DB);
        vstep(whv, DA, DB, lsum);
        ISSUE(c0 + 4, 0 * CB); VMW(6); BAR();
        cstep<2 * CB>(lds, ro0, ro1, ROWOK(c0 + 2), whf, DA);
        vstep(whv, DB, DA, lsum);
        ISSUE(c0 + 5, 1 * CB); VMW(6); BAR();
        cstep<3 * CB>(lds, ro0, ro1, ROWOK(c0 + 3), whf, DB);
        vstep(whv, DA, DB, lsum);
        ISSUE(c0 + 6, 2 * CB); VMW(6); BAR();
        cstep<0 * CB>(lds, ro0, ro1, ROWOK(c0 + 4), whf, DA);
        vstep(whv, DB, DA, lsum);
    }
    // c = 13
    ISSUE(15, 3 * CB); VMW(6); BAR();
    cstep<1 * CB>(lds, ro0, ro1, ROWOK(13), whf, DB);
    vstep(whv, DA, DB, lsum);
    // c = 14
    ISSUE(16, 0 * CB); VMW(6); BAR();
    cstep<2 * CB>(lds, ro0, ro1, ROWOK(14), whf, DA);
    vstep(whv, DB, DA, lsum);
    // c = 15 (no issue; chunk16's 3 loads outstanding)
    VMW(3); BAR();
    cstep<3 * CB>(lds, ro0, ro1, ROWOK(15), whf, DB);
    vstep(whv, DA, DB, lsum);
    // c = 16
    VMW(0); BAR();
    cstep<0 * CB>(lds, ro0, ro1, ROWOK(16), whf, DA);
    vstep(whv, DB, DA, lsum);
#undef CLMP
#undef ISSUE
#undef VMW
#undef BAR
#undef ROWOK

    // ---- Block reduction -> per-block partial ----
#pragma unroll
    for (int off = 32; off > 0; off >>= 1)
        lsum += __shfl_down(lsum, off, 64);

    if (lane == 0) wsum[wave] = lsum;
    __syncthreads();
    if (tid == 0) {
        float tot = wsum[0] + wsum[1] + wsum[2] + wsum[3];
        const int bid = (bz * GYB + by) * GX + bx;
        partials[bid] = tot;
    }
}

__global__ __launch_bounds__(256)
void ssim_reduce_kernel(const float* __restrict__ partials,
                        float* __restrict__ out)
{
    __shared__ double sm[256];
    double s = 0.0;
    for (int i = threadIdx.x; i < NBLK; i += 256) s += (double)partials[i];
    sm[threadIdx.x] = s;
    __syncthreads();
    for (int stride = 128; stride > 0; stride >>= 1) {
        if (threadIdx.x < stride) sm[threadIdx.x] += sm[threadIdx.x + stride];
        __syncthreads();
    }
    if (threadIdx.x == 0) {
        double mean = sm[0] / (double)((size_t)NPL * IMW * IMH);
        out[0] = (float)(1.0 - mean);
    }
}

extern "C" void kernel_launch(void* const* d_in, const int* in_sizes, int n_in,
                              void* d_out, int out_size, void* d_ws, size_t ws_size,
                              hipStream_t stream)
{
    (void)in_sizes; (void)n_in; (void)out_size; (void)ws_size;
    const float* img1 = (const float*)d_in[0];
    const float* img2 = (const float*)d_in[1];
    float* out = (float*)d_out;

    unsigned int* wbuf = (unsigned int*)d_ws;              // 2 KB weight table
    float* partials = (float*)((char*)d_ws + 4096);        // NBLK floats

    ssim_weight_setup<<<1, 64, 0, stream>>>(wbuf);
    ssim_mfma<<<dim3(NBLK), 256, 0, stream>>>(img1, img2, wbuf, partials);
    ssim_reduce_kernel<<<1, 256, 0, stream>>>(partials, out);
}